// Round 7
// baseline (681.193 us; speedup 1.0000x reference)
//
#include <hip/hip_runtime.h>

typedef __bf16 bf16_t;
typedef bf16_t bf16x8 __attribute__((ext_vector_type(8)));
typedef bf16_t bf16x4 __attribute__((ext_vector_type(4)));
typedef float f32x4 __attribute__((ext_vector_type(4)));
typedef float f32x8_t __attribute__((ext_vector_type(8)));

#define BATCH 16384
#define KDIM  1024
#define NCOLS 9216   // [0,3072) ig | [3072,4096) ii | [4096,5120) ih | [5120,8192) hg | [8192,9216) hh

#define BM 128
#define BN 128
#define BK 32

// ---------------- one-dispatch cast/concat (unchanged from R6) ----------------
__global__ __launch_bounds__(256)
void cast_all(const float* __restrict__ Wig, const float* __restrict__ Wii,
              const float* __restrict__ Wih, const float* __restrict__ Whg,
              const float* __restrict__ Whh,
              const float* __restrict__ big, const float* __restrict__ bii,
              const float* __restrict__ bih, const float* __restrict__ bhg,
              const float* __restrict__ bhh,
              const float* __restrict__ inp, const float* __restrict__ hid,
              bf16_t* __restrict__ Wcat, float* __restrict__ bcat,
              bf16_t* __restrict__ inpb, bf16_t* __restrict__ hidb,
              int nact_units, int ntot)
{
  int u = blockIdx.x * 256 + threadIdx.x;
  if (u >= ntot) return;

  if (u < 2359296) {   // weights
    const float* src; int off;
    if      (u < 786432)  { src = Wig; off = u; }
    else if (u < 1048576) { src = Wii; off = u - 786432; }
    else if (u < 1310720) { src = Wih; off = u - 1048576; }
    else if (u < 2097152) { src = Whg; off = u - 1310720; }
    else                  { src = Whh; off = u - 2097152; }
    float4 v = reinterpret_cast<const float4*>(src)[off];
    bf16x4 o;
    o[0] = (bf16_t)v.x; o[1] = (bf16_t)v.y; o[2] = (bf16_t)v.z; o[3] = (bf16_t)v.w;
    reinterpret_cast<bf16x4*>(Wcat)[u] = o;
  } else if (u < 2361600) {  // biases
    int bu = u - 2359296;
    int i = bu * 4;
    const float* src; int off;
    if      (i < 3072) { src = big; off = i; }
    else if (i < 4096) { src = bii; off = i - 3072; }
    else if (i < 5120) { src = bih; off = i - 4096; }
    else if (i < 8192) { src = bhg; off = i - 5120; }
    else               { src = bhh; off = i - 8192; }
    reinterpret_cast<float4*>(bcat)[bu] = *reinterpret_cast<const float4*>(src + off);
  } else {                    // activations
    int au = u - 2361600;
    const float* src; bf16_t* dst; int off;
    if (au < nact_units) { src = inp; dst = inpb; off = au; }
    else                 { src = hid; dst = hidb; off = au - nact_units; }
    float4 v = reinterpret_cast<const float4*>(src)[off];
    bf16x4 o;
    o[0] = (bf16_t)v.x; o[1] = (bf16_t)v.y; o[2] = (bf16_t)v.z; o[3] = (bf16_t)v.w;
    reinterpret_cast<bf16x4*>(dst)[off] = o;
  }
}

// fallback per-chunk act cast
__global__ __launch_bounds__(256)
void cast_acts(const float* __restrict__ inp, const float* __restrict__ hid,
               bf16_t* __restrict__ inpb, bf16_t* __restrict__ hidb, int n4) {
  int i = blockIdx.x * 256 + threadIdx.x;
  if (i >= 2 * n4) return;
  const float* src = (i < n4) ? inp : hid;
  bf16_t* dst = (i < n4) ? inpb : hidb;
  int off = (i < n4) ? i : i - n4;
  float4 v = reinterpret_cast<const float4*>(src)[off];
  bf16x4 o;
  o[0] = (bf16_t)v.x; o[1] = (bf16_t)v.y; o[2] = (bf16_t)v.z; o[3] = (bf16_t)v.w;
  reinterpret_cast<bf16x4*>(dst)[off] = o;
}

// ---------------- GEMM: exact R2/R6 structure (measured 330 us, VGPR 68) ----------------
__global__ __launch_bounds__(256)
void gemm_preln(const bf16_t* __restrict__ inpb, const bf16_t* __restrict__ hidb,
                const bf16_t* __restrict__ Wcat, const float* __restrict__ bcat,
                bf16_t* __restrict__ preLN)
{
  __shared__ alignas(16) bf16_t As[2][BM * BK];
  __shared__ alignas(16) bf16_t Bs[2][BN * BK];
  const int tid  = threadIdx.x;
  const int wid  = tid >> 6;
  const int lane = tid & 63;
  const int row0 = blockIdx.x * BM;
  const int col0 = blockIdx.y * BN;
  const bf16_t* __restrict__ act = (col0 < 5120) ? inpb : hidb;
  const bf16_t* __restrict__ wgt = Wcat + (size_t)col0 * KDIM;

  f32x4 acc[4][4] = {};

  const int wr = wid >> 1, wc = wid & 1;
  const int fr = lane & 15;
  const int kg = lane >> 4;

  auto stage = [&](int buf, int kt) {
    const int k0 = kt * BK;
    #pragma unroll
    for (int c = 0; c < 2; ++c) {
      const int e = c * 2048 + tid * 8;
      const int r = e >> 5, kk = e & 31;
      const bf16_t* ga = act + (size_t)(row0 + r) * KDIM + (k0 + kk);
      const bf16_t* gb = wgt + (size_t)r * KDIM + (k0 + kk);
      __builtin_amdgcn_global_load_lds(
          (const __attribute__((address_space(1))) unsigned int*)ga,
          (__attribute__((address_space(3))) unsigned int*)&As[buf][c * 2048 + wid * 512],
          16, 0, 0);
      __builtin_amdgcn_global_load_lds(
          (const __attribute__((address_space(1))) unsigned int*)gb,
          (__attribute__((address_space(3))) unsigned int*)&Bs[buf][c * 2048 + wid * 512],
          16, 0, 0);
    }
  };

  auto compute = [&](int buf) {
    bf16x8 a[4], b[4];
    #pragma unroll
    for (int m = 0; m < 4; ++m)
      a[m] = *(const bf16x8*)&As[buf][(wr * 64 + m * 16 + fr) * BK + kg * 8];
    #pragma unroll
    for (int n = 0; n < 4; ++n)
      b[n] = *(const bf16x8*)&Bs[buf][(wc * 64 + n * 16 + fr) * BK + kg * 8];
    #pragma unroll
    for (int m = 0; m < 4; ++m)
      #pragma unroll
      for (int n = 0; n < 4; ++n)
        acc[m][n] = __builtin_amdgcn_mfma_f32_16x16x32_bf16(a[m], b[n], acc[m][n], 0, 0, 0);
  };

  stage(0, 0);
  __syncthreads();
  int cur = 0;
  const int NT = KDIM / BK;
  for (int t = 0; t < NT; ++t) {
    if (t + 1 < NT) stage(cur ^ 1, t + 1);
    compute(cur);
    __syncthreads();
    cur ^= 1;
  }

  const int orow = row0 + wr * 64;
  const int ocol = col0 + wc * 64;
  #pragma unroll
  for (int n = 0; n < 4; ++n) {
    const int col = ocol + n * 16 + fr;
    const float bias = bcat[col];
    #pragma unroll
    for (int m = 0; m < 4; ++m) {
      const int rbase = orow + m * 16 + kg * 4;
      #pragma unroll
      for (int j = 0; j < 4; ++j)
        preLN[(size_t)(rbase + j) * NCOLS + col] = (bf16_t)(acc[m][n][j] + bias);
    }
  }
}

// ---------------- row stats: one wave per row, barrier-free, 16B coalesced ----------------
// unit u = j*64+ln covers elems [u*8,u*8+8); segment boundaries (384/512/640/1024 units)
// are multiples of 64 -> segment is compile-time per j.
__global__ __launch_bounds__(256)
void row_stats(const bf16_t* __restrict__ preLN, float* __restrict__ stats, int crows)
{
  const int ln  = threadIdx.x & 63;
  const int row = blockIdx.x * 4 + (threadIdx.x >> 6);
  if (row >= crows) return;
  const bf16_t* __restrict__ src = preLN + (size_t)row * NCOLS;

  float s1[5] = {0.f,0.f,0.f,0.f,0.f}, s2[5] = {0.f,0.f,0.f,0.f,0.f};
  #pragma unroll
  for (int j = 0; j < 18; ++j) {
    const int sg = (j < 6) ? 0 : (j < 8) ? 1 : (j < 10) ? 2 : (j < 16) ? 3 : 4;
    bf16x8 v = *(const bf16x8*)(src + (size_t)(j * 64 + ln) * 8);
    #pragma unroll
    for (int t = 0; t < 8; ++t) {
      float f = (float)v[t];
      s1[sg] += f;
      s2[sg] += f * f;
    }
  }
  #pragma unroll
  for (int s = 0; s < 5; ++s)
    #pragma unroll
    for (int off = 32; off; off >>= 1) {
      s1[s] += __shfl_xor(s1[s], off);
      s2[s] += __shfl_xor(s2[s], off);
    }
  if (ln == 0) {
    const float nn[5] = {3072.f, 1024.f, 1024.f, 3072.f, 1024.f};
    float* st = stats + (size_t)row * 10;
    #pragma unroll
    for (int s = 0; s < 5; ++s) {          // static indexing only (rule #20)
      float mu = s1[s] / nn[s];
      st[s] = mu;
      st[5 + s] = rsqrtf(s2[s] / nn[s] - mu * mu + 1e-5f);
    }
  }
}

// ---------------- elementwise combine: 8 cols/thread, fully coalesced ----------------
__device__ __forceinline__ f32x8_t ld8f(const float* __restrict__ p) {
  f32x8_t r;
  *(float4*)&r       = *(const float4*)p;
  *((float4*)&r + 1) = *(const float4*)(p + 4);
  return r;
}
__device__ __forceinline__ f32x8_t cvt8(bf16x8 v) {
  f32x8_t r;
  #pragma unroll
  for (int i = 0; i < 8; ++i) r[i] = (float)v[i];
  return r;
}

__global__ __launch_bounds__(256)
void combine(const bf16_t* __restrict__ preLN, const float* __restrict__ stats,
             const float* __restrict__ hidden,
             const float* __restrict__ g_ig, const float* __restrict__ be_ig,
             const float* __restrict__ g_hg, const float* __restrict__ be_hg,
             const float* __restrict__ g_ii, const float* __restrict__ be_ii,
             const float* __restrict__ g_ih, const float* __restrict__ be_ih,
             const float* __restrict__ g_hh, const float* __restrict__ be_hh,
             float* __restrict__ out, int crows)
{
  int id = blockIdx.x * 256 + threadIdx.x;   // one 8-col unit
  if (id >= crows * 128) return;
  const int row = id >> 7;
  const int c0  = (id & 127) * 8;

  const float* __restrict__ st = stats + (size_t)row * 10;
  const float mu0 = st[0], mu1 = st[1], mu2 = st[2], mu3 = st[3], mu4 = st[4];
  const float r0 = st[5], r1 = st[6], r2 = st[7], r3 = st[8], r4 = st[9];

  const bf16_t* __restrict__ src = preLN + (size_t)row * NCOLS + c0;
  f32x8_t x_igr = cvt8(*(const bf16x8*)(src));
  f32x8_t x_igz = cvt8(*(const bf16x8*)(src + 1024));
  f32x8_t x_igg = cvt8(*(const bf16x8*)(src + 2048));
  f32x8_t x_ii  = cvt8(*(const bf16x8*)(src + 3072));
  f32x8_t x_ih  = cvt8(*(const bf16x8*)(src + 4096));
  f32x8_t x_hgr = cvt8(*(const bf16x8*)(src + 5120));
  f32x8_t x_hgz = cvt8(*(const bf16x8*)(src + 6144));
  f32x8_t x_hgg = cvt8(*(const bf16x8*)(src + 7168));
  f32x8_t x_hh  = cvt8(*(const bf16x8*)(src + 8192));

  f32x8_t pr = (x_igr - mu0) * r0 * ld8f(g_ig + c0)        + ld8f(be_ig + c0)
             + (x_hgr - mu3) * r3 * ld8f(g_hg + c0)        + ld8f(be_hg + c0);
  f32x8_t pz = (x_igz - mu0) * r0 * ld8f(g_ig + c0 + 1024) + ld8f(be_ig + c0 + 1024)
             + (x_hgz - mu3) * r3 * ld8f(g_hg + c0 + 1024) + ld8f(be_hg + c0 + 1024);
  f32x8_t pg = (x_igg - mu0) * r0 * ld8f(g_ig + c0 + 2048) + ld8f(be_ig + c0 + 2048)
             + (x_hgg - mu3) * r3 * ld8f(g_hg + c0 + 2048) + ld8f(be_hg + c0 + 2048);

  f32x8_t Hx = (x_ii - mu1) * r1 * ld8f(g_ii + c0) + ld8f(be_ii + c0);
  f32x8_t xh = (x_ih - mu2) * r2 * ld8f(g_ih + c0) + ld8f(be_ih + c0);
  f32x8_t hh = (x_hh - mu4) * r4 * ld8f(g_hh + c0) + ld8f(be_hh + c0);

  f32x8_t hv = ld8f(hidden + (size_t)row * 1024 + c0);

  f32x8_t o;
  #pragma unroll
  for (int i = 0; i < 8; ++i) {
    float rr = 1.f / (1.f + __expf(-pr[i]));
    float zz = 1.f / (1.f + __expf(-pz[i]));
    float gg = 1.f / (1.f + __expf(-pg[i]));
    float pre = (1.f - rr) * xh[i] + rr * hh[i];
    float hm  = 1.f - 2.f / (1.f + __expf(2.f * pre));   // tanh
    o[i] = ((1.f - zz) * hv[i] + zz * hm) * (1.f - gg) + gg * Hx[i];
  }
  float* __restrict__ dst = out + (size_t)row * 1024 + c0;
  *(float4*)dst       = *(float4*)&o;
  *((float4*)dst + 1) = *((float4*)&o + 1);
}

extern "C" void kernel_launch(void* const* d_in, const int* in_sizes, int n_in,
                              void* d_out, int out_size, void* d_ws, size_t ws_size,
                              hipStream_t stream) {
  const float* inp      = (const float*)d_in[0];
  const float* hidden   = (const float*)d_in[1];
  const float* W_i2gate = (const float*)d_in[2];
  const float* b_i2gate = (const float*)d_in[3];
  const float* W_h2gate = (const float*)d_in[4];
  const float* b_h2gate = (const float*)d_in[5];
  const float* W_i2i    = (const float*)d_in[6];
  const float* b_i2i    = (const float*)d_in[7];
  const float* W_i2h    = (const float*)d_in[8];
  const float* b_i2h    = (const float*)d_in[9];
  const float* W_h2h    = (const float*)d_in[10];
  const float* b_h2h    = (const float*)d_in[11];
  const float* g_ig  = (const float*)d_in[12];
  const float* be_ig = (const float*)d_in[13];
  const float* g_hg  = (const float*)d_in[14];
  const float* be_hg = (const float*)d_in[15];
  const float* g_ii  = (const float*)d_in[16];
  const float* be_ii = (const float*)d_in[17];
  const float* g_ih  = (const float*)d_in[18];
  const float* be_ih = (const float*)d_in[19];
  const float* g_hh  = (const float*)d_in[20];
  const float* be_hh = (const float*)d_in[21];
  float* out = (float*)d_out;

  const size_t WCAT_B  = (size_t)NCOLS * KDIM * 2;     // 18,874,368
  const size_t BCAT_B  = (size_t)NCOLS * 4;            // 36,864
  const size_t FIXED_B = WCAT_B + BCAT_B;
  const size_t PER_ROW = 40 + 2048 + 2048 + 18432;     // 22,568

  if (ws_size < FIXED_B + PER_ROW * 256) return;       // visible fail, no OOB

  char* ws = (char*)d_ws;
  bf16_t* Wcat = (bf16_t*)ws;
  float*  bcat = (float*)(ws + WCAT_B);
  char*   dyn  = ws + FIXED_B;

  size_t max_rows = (ws_size - FIXED_B) / PER_ROW;
  int chunk = (int)((max_rows / 256) * 256);
  if (chunk > BATCH) chunk = BATCH;

  float*  stats = (float*)dyn;
  bf16_t* inpb  = (bf16_t*)(dyn + (size_t)chunk * 40);
  bf16_t* hidb  = (bf16_t*)(dyn + (size_t)chunk * (40 + 2048));
  bf16_t* preLN = (bf16_t*)(dyn + (size_t)chunk * (40 + 4096));

  if (chunk == BATCH) {
    // hot path: 4 dispatches total
    const int nact = BATCH * KDIM / 4;
    const int ntot = 2361600 + 2 * nact;
    cast_all<<<(ntot + 255) / 256, 256, 0, stream>>>(
        W_i2gate, W_i2i, W_i2h, W_h2gate, W_h2h,
        b_i2gate, b_i2i, b_i2h, b_h2gate, b_h2h,
        inp, hidden, Wcat, bcat, inpb, hidb, nact, ntot);

    dim3 ggrid(BATCH / BM, NCOLS / BN);
    gemm_preln<<<ggrid, 256, 0, stream>>>(inpb, hidb, Wcat, bcat, preLN);

    row_stats<<<BATCH / 4, 256, 0, stream>>>(preLN, stats, BATCH);

    combine<<<BATCH * 128 / 256, 256, 0, stream>>>(preLN, stats, hidden,
                                       g_ig, be_ig, g_hg, be_hg,
                                       g_ii, be_ii, g_ih, be_ih, g_hh, be_hh,
                                       out, BATCH);
  } else {
    const int ntot_w = 2361600;
    cast_all<<<(ntot_w + 255) / 256, 256, 0, stream>>>(
        W_i2gate, W_i2i, W_i2h, W_h2gate, W_h2h,
        b_i2gate, b_i2i, b_i2h, b_h2gate, b_h2h,
        nullptr, nullptr, Wcat, bcat, nullptr, nullptr, 0, ntot_w);

    for (int r0 = 0; r0 < BATCH; r0 += chunk) {
      int cr = BATCH - r0;
      if (cr > chunk) cr = chunk;
      int n4 = cr * KDIM / 4;
      cast_acts<<<(2 * n4 + 255) / 256, 256, 0, stream>>>(
          inp + (size_t)r0 * KDIM, hidden + (size_t)r0 * KDIM, inpb, hidb, n4);

      dim3 ggrid(cr / BM, NCOLS / BN);
      gemm_preln<<<ggrid, 256, 0, stream>>>(inpb, hidb, Wcat, bcat, preLN);

      row_stats<<<cr / 4, 256, 0, stream>>>(preLN, stats, cr);

      combine<<<cr * 128 / 256, 256, 0, stream>>>(preLN, stats,
                                         hidden + (size_t)r0 * KDIM,
                                         g_ig, be_ig, g_hg, be_hg,
                                         g_ii, be_ii, g_ih, be_ih, g_hh, be_hh,
                                         out + (size_t)r0 * KDIM, cr);
    }
  }
}

// Round 8
// 603.616 us; speedup vs baseline: 1.1285x; 1.1285x over previous
//
#include <hip/hip_runtime.h>

typedef __bf16 bf16_t;
typedef bf16_t bf16x8 __attribute__((ext_vector_type(8)));
typedef bf16_t bf16x4 __attribute__((ext_vector_type(4)));
typedef float f32x4 __attribute__((ext_vector_type(4)));

#define BATCH 16384
#define KDIM  1024
#define NCOLS 9216   // [0,3072) ig | [3072,4096) ii | [4096,5120) ih | [5120,8192) hg | [8192,9216) hh

#define BMg 256
#define BNg 256
#define BKg 64
#define NTg (KDIM / BKg)   // 16 K-tiles
#define NBN (NCOLS / BNg)  // 36

// ---------------- one-dispatch cast/concat (R6, measured-good) ----------------
__global__ __launch_bounds__(256)
void cast_all(const float* __restrict__ Wig, const float* __restrict__ Wii,
              const float* __restrict__ Wih, const float* __restrict__ Whg,
              const float* __restrict__ Whh,
              const float* __restrict__ big, const float* __restrict__ bii,
              const float* __restrict__ bih, const float* __restrict__ bhg,
              const float* __restrict__ bhh,
              const float* __restrict__ inp, const float* __restrict__ hid,
              bf16_t* __restrict__ Wcat, float* __restrict__ bcat,
              bf16_t* __restrict__ inpb, bf16_t* __restrict__ hidb,
              int nact_units, int ntot)
{
  int u = blockIdx.x * 256 + threadIdx.x;
  if (u >= ntot) return;

  if (u < 2359296) {   // weights
    const float* src; int off;
    if      (u < 786432)  { src = Wig; off = u; }
    else if (u < 1048576) { src = Wii; off = u - 786432; }
    else if (u < 1310720) { src = Wih; off = u - 1048576; }
    else if (u < 2097152) { src = Whg; off = u - 1310720; }
    else                  { src = Whh; off = u - 2097152; }
    float4 v = reinterpret_cast<const float4*>(src)[off];
    bf16x4 o;
    o[0] = (bf16_t)v.x; o[1] = (bf16_t)v.y; o[2] = (bf16_t)v.z; o[3] = (bf16_t)v.w;
    reinterpret_cast<bf16x4*>(Wcat)[u] = o;
  } else if (u < 2361600) {  // biases
    int bu = u - 2359296;
    int i = bu * 4;
    const float* src; int off;
    if      (i < 3072) { src = big; off = i; }
    else if (i < 4096) { src = bii; off = i - 3072; }
    else if (i < 5120) { src = bih; off = i - 4096; }
    else if (i < 8192) { src = bhg; off = i - 5120; }
    else               { src = bhh; off = i - 8192; }
    reinterpret_cast<float4*>(bcat)[bu] = *reinterpret_cast<const float4*>(src + off);
  } else {                    // activations
    int au = u - 2361600;
    const float* src; bf16_t* dst; int off;
    if (au < nact_units) { src = inp; dst = inpb; off = au; }
    else                 { src = hid; dst = hidb; off = au - nact_units; }
    float4 v = reinterpret_cast<const float4*>(src)[off];
    bf16x4 o;
    o[0] = (bf16_t)v.x; o[1] = (bf16_t)v.y; o[2] = (bf16_t)v.z; o[3] = (bf16_t)v.w;
    reinterpret_cast<bf16x4*>(dst)[off] = o;
  }
}

__global__ __launch_bounds__(256)
void cast_acts(const float* __restrict__ inp, const float* __restrict__ hid,
               bf16_t* __restrict__ inpb, bf16_t* __restrict__ hidb, int n4) {
  int i = blockIdx.x * 256 + threadIdx.x;
  if (i >= 2 * n4) return;
  const float* src = (i < n4) ? inp : hid;
  bf16_t* dst = (i < n4) ? inpb : hidb;
  int off = (i < n4) ? i : i - n4;
  float4 v = reinterpret_cast<const float4*>(src)[off];
  bf16x4 o;
  o[0] = (bf16_t)v.x; o[1] = (bf16_t)v.y; o[2] = (bf16_t)v.z; o[3] = (bf16_t)v.w;
  reinterpret_cast<bf16x4*>(dst)[off] = o;
}

// ---------------- GEMM: 256x256, BK=64, 8 waves, phase-scheduled counted-vmcnt ----------------
// LDS: [2 buf][A|B][2 half][2 kpanel][128 rows][32 cols] bf16 = 128 KiB.
// Per-wave C: rows {qm*128 + wr*64 ..+64} x cols {qn*128 + wc*32 ..+32}, qm,qn in {0,1}.
// Phase q=(qm,qn): ph1(0,0) ph2(0,1) ph3(1,0) ph4(1,1).
//   A-h0 read ph1,ph2 (dead after ph2); B-h0 read ph1,ph3 (dead after ph3);
//   A-h1 read ph3,ph4; B-h1 read ph2,ph4 (dead at group end).
// Stage schedule (into buffer T%2 / (T+1)%2, 1 half-tile per phase, all after-death):
//   ph1(T): A-h1(T+1)  ph2(T): B-h1(T+1)  ph3(T): A-h0(T+2)  ph4(T): B-h0(T+2)
// Waits: vmcnt(4) at group end only (invariant: entering group T, tile T fully landed,
// 2 half-tiles of T+1 in flight). Tail: vmcnt(0) at T=NTg-2.
__global__ __launch_bounds__(512, 1)
void gemm_preln(const bf16_t* __restrict__ inpb, const bf16_t* __restrict__ hidb,
                const bf16_t* __restrict__ Wcat, const float* __restrict__ bcat,
                bf16_t* __restrict__ preLN, int nbm)
{
  __shared__ alignas(16) char lds_raw[131072];

  const int tid  = threadIdx.x;
  const int wid  = tid >> 6;         // 0..7
  const int lane = tid & 63;
  const int fr   = lane & 15;
  const int kg   = lane >> 4;        // 0..3
  const int wr   = wid >> 2;         // 0..1
  const int wc   = wid & 3;          // 0..3

  // XCD-aware bijective block swizzle
  const int nwg = nbm * NBN;
  int orig = blockIdx.x;
  int q_ = nwg >> 3, r_ = nwg & 7, xcd = orig & 7, idx = orig >> 3;
  int wg = (xcd < r_ ? xcd * (q_ + 1) : r_ * (q_ + 1) + (xcd - r_) * q_) + idx;
  const int bm = wg / NBN, bn = wg % NBN;
  const int row0 = bm * BMg, col0 = bn * BNg;
  const bf16_t* __restrict__ act = (col0 < 5120) ? inpb : hidb;
  const bf16_t* __restrict__ wgt = Wcat + (size_t)col0 * KDIM;

  // staging source: thread covers (r_st, k8_st) of each [128][32] kpanel (linear layout)
  const int r_st  = tid >> 2;        // 0..127
  const int k8_st = tid & 3;         // 0..3
  const bf16_t* pA = act + (size_t)(row0 + r_st) * KDIM + k8_st * 8;
  const bf16_t* pB = wgt + (size_t)r_st * KDIM + k8_st * 8;

  // stage one half-tile (2 x global_load_lds, kpanels 0/1); dest wave-uniform
  auto stage_half = [&](int mat, int h, int T) {
    const bf16_t* s = (mat ? pB : pA) + ((size_t)h * 128) * KDIM + T * BKg;
    char* d = lds_raw + ((T & 1) << 16) + (mat << 15) + (h << 14) + (wid << 10);
    __builtin_amdgcn_global_load_lds(
        (const __attribute__((address_space(1))) unsigned int*)s,
        (__attribute__((address_space(3))) unsigned int*)d, 16, 0, 0);
    __builtin_amdgcn_global_load_lds(
        (const __attribute__((address_space(1))) unsigned int*)(s + 32),
        (__attribute__((address_space(3))) unsigned int*)(d + 8192), 16, 0, 0);
  };

  // ds-read offsets (within a 16-KiB half region); wave reads contiguous 1KB -> 2-way free
  int offA[4][2], offB[2][2];
  #pragma unroll
  for (int m = 0; m < 4; ++m)
    #pragma unroll
    for (int ks = 0; ks < 2; ++ks)
      offA[m][ks] = ks * 8192 + (wr * 64 + m * 16 + fr) * 64 + kg * 16;
  #pragma unroll
  for (int n = 0; n < 2; ++n)
    #pragma unroll
    for (int ks = 0; ks < 2; ++ks)
      offB[n][ks] = ks * 8192 + (wc * 32 + n * 16 + fr) * 64 + kg * 16;

  f32x4 acc[2][4][2][2] = {};   // [qm][m][qn][n]

  // prologue: tile0 all 4 halves + tile1 h0 halves (12 loads)
  stage_half(0, 0, 0); stage_half(1, 0, 0);
  stage_half(0, 1, 0); stage_half(1, 1, 0);
  stage_half(0, 0, 1); stage_half(1, 0, 1);
  asm volatile("s_waitcnt vmcnt(4)" ::: "memory");
  __builtin_amdgcn_s_barrier();

  for (int T = 0; T < NTg; ++T) {
    const int bufo = (T & 1) << 16;
    #pragma unroll
    for (int ph = 0; ph < 4; ++ph) {
      const int qm = ph >> 1, qn = ph & 1;
      bf16x8 a[4][2], b[2][2];
      #pragma unroll
      for (int m = 0; m < 4; ++m)
        #pragma unroll
        for (int ks = 0; ks < 2; ++ks)
          a[m][ks] = *(const bf16x8*)(lds_raw + bufo + qm * 16384 + offA[m][ks]);
      #pragma unroll
      for (int n = 0; n < 2; ++n)
        #pragma unroll
        for (int ks = 0; ks < 2; ++ks)
          b[n][ks] = *(const bf16x8*)(lds_raw + bufo + 32768 + qn * 16384 + offB[n][ks]);

      if      (ph == 0) { if (T + 1 < NTg) stage_half(0, 1, T + 1); }
      else if (ph == 1) { if (T + 1 < NTg) stage_half(1, 1, T + 1); }
      else if (ph == 2) { if (T + 2 < NTg) stage_half(0, 0, T + 2); }
      else              { if (T + 2 < NTg) stage_half(1, 0, T + 2); }

      __builtin_amdgcn_s_barrier();
      asm volatile("s_waitcnt lgkmcnt(0)" ::: "memory");
      __builtin_amdgcn_sched_barrier(0);

      __builtin_amdgcn_s_setprio(1);
      #pragma unroll
      for (int m = 0; m < 4; ++m)
        #pragma unroll
        for (int n = 0; n < 2; ++n)
          #pragma unroll
          for (int ks = 0; ks < 2; ++ks)
            acc[qm][m][qn][n] = __builtin_amdgcn_mfma_f32_16x16x32_bf16(
                a[m][ks], b[n][ks], acc[qm][m][qn][n], 0, 0, 0);
      __builtin_amdgcn_s_setprio(0);

      if (ph < 3) __builtin_amdgcn_s_barrier();
    }
    // group end: counted drain + barrier (skip after the last group)
    if (T < NTg - 2) {
      asm volatile("s_waitcnt vmcnt(4)" ::: "memory");
      __builtin_amdgcn_s_barrier();
    } else if (T == NTg - 2) {
      asm volatile("s_waitcnt vmcnt(0)" ::: "memory");
      __builtin_amdgcn_s_barrier();
    }
  }

  // epilogue: bias + bf16 store. C/D 16x16: col=lane&15, row=(lane>>4)*4+j (verified R2)
  #pragma unroll
  for (int qn_ = 0; qn_ < 2; ++qn_)
    #pragma unroll
    for (int n = 0; n < 2; ++n) {
      const int col = col0 + qn_ * 128 + wc * 32 + n * 16 + fr;
      const float bias = bcat[col];
      #pragma unroll
      for (int qm_ = 0; qm_ < 2; ++qm_)
        #pragma unroll
        for (int m = 0; m < 4; ++m) {
          const int rbase = row0 + qm_ * 128 + wr * 64 + m * 16 + kg * 4;
          #pragma unroll
          for (int j = 0; j < 4; ++j)
            preLN[(size_t)(rbase + j) * NCOLS + col] = (bf16_t)(acc[qm_][m][qn_][n][j] + bias);
        }
    }
}

// ---------------- fused LN + gates + combine (R6, measured-good) ----------------
__global__ __launch_bounds__(256)
void ln_combine(const bf16_t* __restrict__ preLN, const float* __restrict__ hidden,
                const float* __restrict__ g_ig, const float* __restrict__ be_ig,
                const float* __restrict__ g_hg, const float* __restrict__ be_hg,
                const float* __restrict__ g_ii, const float* __restrict__ be_ii,
                const float* __restrict__ g_ih, const float* __restrict__ be_ih,
                const float* __restrict__ g_hh, const float* __restrict__ be_hh,
                float* __restrict__ out)
{
  __shared__ alignas(16) bf16_t rowbuf[NCOLS];
  __shared__ float wsum[4][10];
  __shared__ float stats[10];
  const int tid = threadIdx.x;
  const int wv  = tid >> 6;
  const int ln  = tid & 63;
  const size_t row = blockIdx.x;
  const bf16_t* __restrict__ src = preLN + row * NCOLS;

  float s1[5] = {0.f, 0.f, 0.f, 0.f, 0.f};
  float s2[5] = {0.f, 0.f, 0.f, 0.f, 0.f};
  #pragma unroll
  for (int j = 0; j < 9; ++j) {
    const int idx = j * 1024 + tid * 4;
    bf16x4 v = *(const bf16x4*)&src[idx];
    *(bf16x4*)&rowbuf[idx] = v;
    const int sg = (j < 3) ? 0 : (j == 3) ? 1 : (j == 4) ? 2 : (j < 8) ? 3 : 4;
    const float f0 = (float)v[0], f1 = (float)v[1], f2 = (float)v[2], f3 = (float)v[3];
    s1[sg] += f0 + f1 + f2 + f3;
    s2[sg] += f0 * f0 + f1 * f1 + f2 * f2 + f3 * f3;
  }
  #pragma unroll
  for (int s = 0; s < 5; ++s)
    #pragma unroll
    for (int off = 32; off; off >>= 1) {
      s1[s] += __shfl_xor(s1[s], off);
      s2[s] += __shfl_xor(s2[s], off);
    }
  if (ln == 0) {
    #pragma unroll
    for (int s = 0; s < 5; ++s) { wsum[wv][s] = s1[s]; wsum[wv][5 + s] = s2[s]; }
  }
  __syncthreads();
  if (tid < 5) {
    const float n = (tid == 0 || tid == 3) ? 3072.f : 1024.f;
    float t1 = wsum[0][tid] + wsum[1][tid] + wsum[2][tid] + wsum[3][tid];
    float t2 = wsum[0][5 + tid] + wsum[1][5 + tid] + wsum[2][5 + tid] + wsum[3][5 + tid];
    float mu = t1 / n;
    float var = t2 / n - mu * mu;
    stats[tid] = mu;
    stats[5 + tid] = rsqrtf(var + 1e-5f);
  }
  __syncthreads();

  const float mu0 = stats[0], r0 = stats[5];
  const float mu1 = stats[1], r1 = stats[6];
  const float mu2 = stats[2], r2 = stats[7];
  const float mu3 = stats[3], r3 = stats[8];
  const float mu4 = stats[4], r4 = stats[9];
  const float* __restrict__ hrow = hidden + row * 1024;

  #pragma unroll
  for (int k = 0; k < 4; ++k) {
    const int c = tid + k * 256;
    float x_igr = (float)rowbuf[c];
    float x_igz = (float)rowbuf[c + 1024];
    float x_igg = (float)rowbuf[c + 2048];
    float x_ii  = (float)rowbuf[3072 + c];
    float x_ih  = (float)rowbuf[4096 + c];
    float x_hgr = (float)rowbuf[5120 + c];
    float x_hgz = (float)rowbuf[6144 + c];
    float x_hgg = (float)rowbuf[7168 + c];
    float x_hh  = (float)rowbuf[8192 + c];

    float pr = (x_igr - mu0) * r0 * g_ig[c]        + be_ig[c]
             + (x_hgr - mu3) * r3 * g_hg[c]        + be_hg[c];
    float pz = (x_igz - mu0) * r0 * g_ig[c + 1024] + be_ig[c + 1024]
             + (x_hgz - mu3) * r3 * g_hg[c + 1024] + be_hg[c + 1024];
    float pg = (x_igg - mu0) * r0 * g_ig[c + 2048] + be_ig[c + 2048]
             + (x_hgg - mu3) * r3 * g_hg[c + 2048] + be_hg[c + 2048];

    float rr = 1.f / (1.f + __expf(-pr));
    float zz = 1.f / (1.f + __expf(-pz));
    float gg = 1.f / (1.f + __expf(-pg));

    float Hx = (x_ii - mu1) * r1 * g_ii[c] + be_ii[c];
    float xh = (x_ih - mu2) * r2 * g_ih[c] + be_ih[c];
    float hh = (x_hh - mu4) * r4 * g_hh[c] + be_hh[c];

    float hm = tanhf((1.f - rr) * xh + rr * hh);
    float h  = hrow[c];
    out[row * 1024 + c] = ((1.f - zz) * h + zz * hm) * (1.f - gg) + gg * Hx;
  }
}

extern "C" void kernel_launch(void* const* d_in, const int* in_sizes, int n_in,
                              void* d_out, int out_size, void* d_ws, size_t ws_size,
                              hipStream_t stream) {
  const float* inp      = (const float*)d_in[0];
  const float* hidden   = (const float*)d_in[1];
  const float* W_i2gate = (const float*)d_in[2];
  const float* b_i2gate = (const float*)d_in[3];
  const float* W_h2gate = (const float*)d_in[4];
  const float* b_h2gate = (const float*)d_in[5];
  const float* W_i2i    = (const float*)d_in[6];
  const float* b_i2i    = (const float*)d_in[7];
  const float* W_i2h    = (const float*)d_in[8];
  const float* b_i2h    = (const float*)d_in[9];
  const float* W_h2h    = (const float*)d_in[10];
  const float* b_h2h    = (const float*)d_in[11];
  const float* g_ig  = (const float*)d_in[12];
  const float* be_ig = (const float*)d_in[13];
  const float* g_hg  = (const float*)d_in[14];
  const float* be_hg = (const float*)d_in[15];
  const float* g_ii  = (const float*)d_in[16];
  const float* be_ii = (const float*)d_in[17];
  const float* g_ih  = (const float*)d_in[18];
  const float* be_ih = (const float*)d_in[19];
  const float* g_hh  = (const float*)d_in[20];
  const float* be_hh = (const float*)d_in[21];
  float* out = (float*)d_out;

  const size_t WCAT_B  = (size_t)NCOLS * KDIM * 2;     // 18,874,368
  const size_t BCAT_B  = (size_t)NCOLS * 4;            // 36,864
  const size_t FIXED_B = WCAT_B + BCAT_B;
  const size_t PER_ROW = 2048 + 2048 + 18432;          // 22,528

  if (ws_size < FIXED_B + PER_ROW * 256) return;       // visible fail, no OOB

  char* ws = (char*)d_ws;
  bf16_t* Wcat = (bf16_t*)ws;
  float*  bcat = (float*)(ws + WCAT_B);
  char*   dyn  = ws + FIXED_B;

  size_t max_rows = (ws_size - FIXED_B) / PER_ROW;
  int chunk = (int)((max_rows / 256) * 256);
  if (chunk > BATCH) chunk = BATCH;

  bf16_t* inpb  = (bf16_t*)dyn;
  bf16_t* hidb  = (bf16_t*)(dyn + (size_t)chunk * 2048);
  bf16_t* preLN = (bf16_t*)(dyn + (size_t)chunk * 4096);

  if (chunk == BATCH) {
    const int nact = BATCH * KDIM / 4;
    const int ntot = 2361600 + 2 * nact;
    cast_all<<<(ntot + 255) / 256, 256, 0, stream>>>(
        W_i2gate, W_i2i, W_i2h, W_h2gate, W_h2h,
        b_i2gate, b_i2i, b_i2h, b_h2gate, b_h2h,
        inp, hidden, Wcat, bcat, inpb, hidb, nact, ntot);

    int nbm = BATCH / BMg;   // 64
    gemm_preln<<<nbm * NBN, 512, 0, stream>>>(inpb, hidb, Wcat, bcat, preLN, nbm);

    ln_combine<<<BATCH, 256, 0, stream>>>(preLN, hidden,
                                          g_ig, be_ig, g_hg, be_hg,
                                          g_ii, be_ii, g_ih, be_ih, g_hh, be_hh,
                                          out);
  } else {
    const int ntot_w = 2361600;
    cast_all<<<(ntot_w + 255) / 256, 256, 0, stream>>>(
        W_i2gate, W_i2i, W_i2h, W_h2gate, W_h2h,
        b_i2gate, b_i2i, b_i2h, b_h2gate, b_h2h,
        nullptr, nullptr, Wcat, bcat, nullptr, nullptr, 0, ntot_w);

    for (int r0 = 0; r0 < BATCH; r0 += chunk) {
      int cr = BATCH - r0;
      if (cr > chunk) cr = chunk;
      int n4 = cr * KDIM / 4;
      cast_acts<<<(2 * n4 + 255) / 256, 256, 0, stream>>>(
          inp + (size_t)r0 * KDIM, hidden + (size_t)r0 * KDIM, inpb, hidb, n4);

      int nbm = cr / BMg;
      gemm_preln<<<nbm * NBN, 512, 0, stream>>>(inpb, hidb, Wcat, bcat, preLN, nbm);

      ln_combine<<<cr, 256, 0, stream>>>(preLN, hidden + (size_t)r0 * KDIM,
                                         g_ig, be_ig, g_hg, be_hg,
                                         g_ii, be_ii, g_ih, be_ih, g_hh, be_hh,
                                         out + (size_t)r0 * KDIM);
    }
  }
}

// Round 9
// 535.177 us; speedup vs baseline: 1.2728x; 1.1279x over previous
//
#include <hip/hip_runtime.h>

typedef __bf16 bf16_t;
typedef bf16_t bf16x8 __attribute__((ext_vector_type(8)));
typedef bf16_t bf16x4 __attribute__((ext_vector_type(4)));
typedef float f32x4 __attribute__((ext_vector_type(4)));

#define BATCH 16384
#define KDIM  1024
#define NCOLS 9216   // [0,3072) ig | [3072,4096) ii | [4096,5120) ih | [5120,8192) hg | [8192,9216) hh

#define BMg 256
#define BNg 256
#define BKg 64
#define NTg (KDIM / BKg)   // 16 K-tiles
#define NBN (NCOLS / BNg)  // 36

// ---------------- one-dispatch cast/concat (R6, measured-good) ----------------
__global__ __launch_bounds__(256)
void cast_all(const float* __restrict__ Wig, const float* __restrict__ Wii,
              const float* __restrict__ Wih, const float* __restrict__ Whg,
              const float* __restrict__ Whh,
              const float* __restrict__ big, const float* __restrict__ bii,
              const float* __restrict__ bih, const float* __restrict__ bhg,
              const float* __restrict__ bhh,
              const float* __restrict__ inp, const float* __restrict__ hid,
              bf16_t* __restrict__ Wcat, float* __restrict__ bcat,
              bf16_t* __restrict__ inpb, bf16_t* __restrict__ hidb,
              int nact_units, int ntot)
{
  int u = blockIdx.x * 256 + threadIdx.x;
  if (u >= ntot) return;

  if (u < 2359296) {   // weights
    const float* src; int off;
    if      (u < 786432)  { src = Wig; off = u; }
    else if (u < 1048576) { src = Wii; off = u - 786432; }
    else if (u < 1310720) { src = Wih; off = u - 1048576; }
    else if (u < 2097152) { src = Whg; off = u - 1310720; }
    else                  { src = Whh; off = u - 2097152; }
    float4 v = reinterpret_cast<const float4*>(src)[off];
    bf16x4 o;
    o[0] = (bf16_t)v.x; o[1] = (bf16_t)v.y; o[2] = (bf16_t)v.z; o[3] = (bf16_t)v.w;
    reinterpret_cast<bf16x4*>(Wcat)[u] = o;
  } else if (u < 2361600) {  // biases
    int bu = u - 2359296;
    int i = bu * 4;
    const float* src; int off;
    if      (i < 3072) { src = big; off = i; }
    else if (i < 4096) { src = bii; off = i - 3072; }
    else if (i < 5120) { src = bih; off = i - 4096; }
    else if (i < 8192) { src = bhg; off = i - 5120; }
    else               { src = bhh; off = i - 8192; }
    reinterpret_cast<float4*>(bcat)[bu] = *reinterpret_cast<const float4*>(src + off);
  } else {                    // activations
    int au = u - 2361600;
    const float* src; bf16_t* dst; int off;
    if (au < nact_units) { src = inp; dst = inpb; off = au; }
    else                 { src = hid; dst = hidb; off = au - nact_units; }
    float4 v = reinterpret_cast<const float4*>(src)[off];
    bf16x4 o;
    o[0] = (bf16_t)v.x; o[1] = (bf16_t)v.y; o[2] = (bf16_t)v.z; o[3] = (bf16_t)v.w;
    reinterpret_cast<bf16x4*>(dst)[off] = o;
  }
}

__global__ __launch_bounds__(256)
void cast_acts(const float* __restrict__ inp, const float* __restrict__ hid,
               bf16_t* __restrict__ inpb, bf16_t* __restrict__ hidb, int n4) {
  int i = blockIdx.x * 256 + threadIdx.x;
  if (i >= 2 * n4) return;
  const float* src = (i < n4) ? inp : hid;
  bf16_t* dst = (i < n4) ? inpb : hidb;
  int off = (i < n4) ? i : i - n4;
  float4 v = reinterpret_cast<const float4*>(src)[off];
  bf16x4 o;
  o[0] = (bf16_t)v.x; o[1] = (bf16_t)v.y; o[2] = (bf16_t)v.z; o[3] = (bf16_t)v.w;
  reinterpret_cast<bf16x4*>(dst)[off] = o;
}

// ---------------- GEMM: 256x256, BK=64, 8 waves, phase-scheduled counted-vmcnt ----------------
// R8 structure + XOR bank swizzle (the single change vs R8):
//   LDS slot (row r, 16B slot s) holds global chunk k8 = s ^ ((r>>1)&3)  (involution).
//   Write side: global_load_lds stays LINEAR; staging thread (r=tid>>2, s=tid&3) sources
//     global k8 = s ^ ((r>>1)&3) -- the 4 threads of a row still cover one 64B segment.
//   Read side: slot = kg ^ ((row>>1)&3).
//   Bank math: group = 16*(r&1) + 4*slot enumerates all 8 bank-groups over any 8
//   consecutive rows -> 2-way over a 16-lane quarter-wave = free (m136).
__global__ __launch_bounds__(512, 1)
void gemm_preln(const bf16_t* __restrict__ inpb, const bf16_t* __restrict__ hidb,
                const bf16_t* __restrict__ Wcat, const float* __restrict__ bcat,
                bf16_t* __restrict__ preLN, int nbm)
{
  __shared__ alignas(16) char lds_raw[131072];

  const int tid  = threadIdx.x;
  const int wid  = tid >> 6;         // 0..7
  const int lane = tid & 63;
  const int fr   = lane & 15;
  const int kg   = lane >> 4;        // 0..3
  const int wr   = wid >> 2;         // 0..1
  const int wc   = wid & 3;          // 0..3

  // XCD-aware bijective block swizzle
  const int nwg = nbm * NBN;
  int orig = blockIdx.x;
  int q_ = nwg >> 3, r_ = nwg & 7, xcd = orig & 7, idx = orig >> 3;
  int wg = (xcd < r_ ? xcd * (q_ + 1) : r_ * (q_ + 1) + (xcd - r_) * q_) + idx;
  const int bm = wg / NBN, bn = wg % NBN;
  const int row0 = bm * BMg, col0 = bn * BNg;
  const bf16_t* __restrict__ act = (col0 < 5120) ? inpb : hidb;
  const bf16_t* __restrict__ wgt = Wcat + (size_t)col0 * KDIM;

  // staging source: thread covers (r_st, swizzled k8) of each [128][32] kpanel
  const int r_st  = tid >> 2;                       // 0..127
  const int k8_st = (tid & 3) ^ ((r_st >> 1) & 3);  // inverse swizzle on source
  const bf16_t* pA = act + (size_t)(row0 + r_st) * KDIM + k8_st * 8;
  const bf16_t* pB = wgt + (size_t)r_st * KDIM + k8_st * 8;

  // stage one half-tile (2 x global_load_lds, kpanels 0/1); dest wave-uniform, linear
  auto stage_half = [&](int mat, int h, int T) {
    const bf16_t* s = (mat ? pB : pA) + ((size_t)h * 128) * KDIM + T * BKg;
    char* d = lds_raw + ((T & 1) << 16) + (mat << 15) + (h << 14) + (wid << 10);
    __builtin_amdgcn_global_load_lds(
        (const __attribute__((address_space(1))) unsigned int*)s,
        (__attribute__((address_space(3))) unsigned int*)d, 16, 0, 0);
    __builtin_amdgcn_global_load_lds(
        (const __attribute__((address_space(1))) unsigned int*)(s + 32),
        (__attribute__((address_space(3))) unsigned int*)(d + 8192), 16, 0, 0);
  };

  // ds-read offsets (within a 16-KiB half region), swizzled slot
  int offA[4][2], offB[2][2];
  #pragma unroll
  for (int m = 0; m < 4; ++m)
    #pragma unroll
    for (int ks = 0; ks < 2; ++ks) {
      const int rowA = wr * 64 + m * 16 + fr;
      offA[m][ks] = ks * 8192 + rowA * 64 + ((kg ^ ((rowA >> 1) & 3)) << 4);
    }
  #pragma unroll
  for (int n = 0; n < 2; ++n)
    #pragma unroll
    for (int ks = 0; ks < 2; ++ks) {
      const int rowB = wc * 32 + n * 16 + fr;
      offB[n][ks] = ks * 8192 + rowB * 64 + ((kg ^ ((rowB >> 1) & 3)) << 4);
    }

  f32x4 acc[2][4][2][2] = {};   // [qm][m][qn][n]

  // prologue: tile0 all 4 halves + tile1 h0 halves (12 loads)
  stage_half(0, 0, 0); stage_half(1, 0, 0);
  stage_half(0, 1, 0); stage_half(1, 1, 0);
  stage_half(0, 0, 1); stage_half(1, 0, 1);
  asm volatile("s_waitcnt vmcnt(4)" ::: "memory");
  __builtin_amdgcn_s_barrier();

  for (int T = 0; T < NTg; ++T) {
    const int bufo = (T & 1) << 16;
    #pragma unroll
    for (int ph = 0; ph < 4; ++ph) {
      const int qm = ph >> 1, qn = ph & 1;
      bf16x8 a[4][2], b[2][2];
      #pragma unroll
      for (int m = 0; m < 4; ++m)
        #pragma unroll
        for (int ks = 0; ks < 2; ++ks)
          a[m][ks] = *(const bf16x8*)(lds_raw + bufo + qm * 16384 + offA[m][ks]);
      #pragma unroll
      for (int n = 0; n < 2; ++n)
        #pragma unroll
        for (int ks = 0; ks < 2; ++ks)
          b[n][ks] = *(const bf16x8*)(lds_raw + bufo + 32768 + qn * 16384 + offB[n][ks]);

      if      (ph == 0) { if (T + 1 < NTg) stage_half(0, 1, T + 1); }
      else if (ph == 1) { if (T + 1 < NTg) stage_half(1, 1, T + 1); }
      else if (ph == 2) { if (T + 2 < NTg) stage_half(0, 0, T + 2); }
      else              { if (T + 2 < NTg) stage_half(1, 0, T + 2); }

      __builtin_amdgcn_s_barrier();
      asm volatile("s_waitcnt lgkmcnt(0)" ::: "memory");
      __builtin_amdgcn_sched_barrier(0);

      __builtin_amdgcn_s_setprio(1);
      #pragma unroll
      for (int m = 0; m < 4; ++m)
        #pragma unroll
        for (int n = 0; n < 2; ++n)
          #pragma unroll
          for (int ks = 0; ks < 2; ++ks)
            acc[qm][m][qn][n] = __builtin_amdgcn_mfma_f32_16x16x32_bf16(
                a[m][ks], b[n][ks], acc[qm][m][qn][n], 0, 0, 0);
      __builtin_amdgcn_s_setprio(0);

      if (ph < 3) __builtin_amdgcn_s_barrier();
    }
    // group end: counted drain + barrier (skip after the last group)
    if (T < NTg - 2) {
      asm volatile("s_waitcnt vmcnt(4)" ::: "memory");
      __builtin_amdgcn_s_barrier();
    } else if (T == NTg - 2) {
      asm volatile("s_waitcnt vmcnt(0)" ::: "memory");
      __builtin_amdgcn_s_barrier();
    }
  }

  // epilogue: bias + bf16 store. C/D 16x16: col=lane&15, row=(lane>>4)*4+j (verified R2)
  #pragma unroll
  for (int qn_ = 0; qn_ < 2; ++qn_)
    #pragma unroll
    for (int n = 0; n < 2; ++n) {
      const int col = col0 + qn_ * 128 + wc * 32 + n * 16 + fr;
      const float bias = bcat[col];
      #pragma unroll
      for (int qm_ = 0; qm_ < 2; ++qm_)
        #pragma unroll
        for (int m = 0; m < 4; ++m) {
          const int rbase = row0 + qm_ * 128 + wr * 64 + m * 16 + kg * 4;
          #pragma unroll
          for (int j = 0; j < 4; ++j)
            preLN[(size_t)(rbase + j) * NCOLS + col] = (bf16_t)(acc[qm_][m][qn_][n][j] + bias);
        }
    }
}

// ---------------- fused LN + gates + combine (R6, measured-good) ----------------
__global__ __launch_bounds__(256)
void ln_combine(const bf16_t* __restrict__ preLN, const float* __restrict__ hidden,
                const float* __restrict__ g_ig, const float* __restrict__ be_ig,
                const float* __restrict__ g_hg, const float* __restrict__ be_hg,
                const float* __restrict__ g_ii, const float* __restrict__ be_ii,
                const float* __restrict__ g_ih, const float* __restrict__ be_ih,
                const float* __restrict__ g_hh, const float* __restrict__ be_hh,
                float* __restrict__ out)
{
  __shared__ alignas(16) bf16_t rowbuf[NCOLS];
  __shared__ float wsum[4][10];
  __shared__ float stats[10];
  const int tid = threadIdx.x;
  const int wv  = tid >> 6;
  const int ln  = tid & 63;
  const size_t row = blockIdx.x;
  const bf16_t* __restrict__ src = preLN + row * NCOLS;

  float s1[5] = {0.f, 0.f, 0.f, 0.f, 0.f};
  float s2[5] = {0.f, 0.f, 0.f, 0.f, 0.f};
  #pragma unroll
  for (int j = 0; j < 9; ++j) {
    const int idx = j * 1024 + tid * 4;
    bf16x4 v = *(const bf16x4*)&src[idx];
    *(bf16x4*)&rowbuf[idx] = v;
    const int sg = (j < 3) ? 0 : (j == 3) ? 1 : (j == 4) ? 2 : (j < 8) ? 3 : 4;
    const float f0 = (float)v[0], f1 = (float)v[1], f2 = (float)v[2], f3 = (float)v[3];
    s1[sg] += f0 + f1 + f2 + f3;
    s2[sg] += f0 * f0 + f1 * f1 + f2 * f2 + f3 * f3;
  }
  #pragma unroll
  for (int s = 0; s < 5; ++s)
    #pragma unroll
    for (int off = 32; off; off >>= 1) {
      s1[s] += __shfl_xor(s1[s], off);
      s2[s] += __shfl_xor(s2[s], off);
    }
  if (ln == 0) {
    #pragma unroll
    for (int s = 0; s < 5; ++s) { wsum[wv][s] = s1[s]; wsum[wv][5 + s] = s2[s]; }
  }
  __syncthreads();
  if (tid < 5) {
    const float n = (tid == 0 || tid == 3) ? 3072.f : 1024.f;
    float t1 = wsum[0][tid] + wsum[1][tid] + wsum[2][tid] + wsum[3][tid];
    float t2 = wsum[0][5 + tid] + wsum[1][5 + tid] + wsum[2][5 + tid] + wsum[3][5 + tid];
    float mu = t1 / n;
    float var = t2 / n - mu * mu;
    stats[tid] = mu;
    stats[5 + tid] = rsqrtf(var + 1e-5f);
  }
  __syncthreads();

  const float mu0 = stats[0], r0 = stats[5];
  const float mu1 = stats[1], r1 = stats[6];
  const float mu2 = stats[2], r2 = stats[7];
  const float mu3 = stats[3], r3 = stats[8];
  const float mu4 = stats[4], r4 = stats[9];
  const float* __restrict__ hrow = hidden + row * 1024;

  #pragma unroll
  for (int k = 0; k < 4; ++k) {
    const int c = tid + k * 256;
    float x_igr = (float)rowbuf[c];
    float x_igz = (float)rowbuf[c + 1024];
    float x_igg = (float)rowbuf[c + 2048];
    float x_ii  = (float)rowbuf[3072 + c];
    float x_ih  = (float)rowbuf[4096 + c];
    float x_hgr = (float)rowbuf[5120 + c];
    float x_hgz = (float)rowbuf[6144 + c];
    float x_hgg = (float)rowbuf[7168 + c];
    float x_hh  = (float)rowbuf[8192 + c];

    float pr = (x_igr - mu0) * r0 * g_ig[c]        + be_ig[c]
             + (x_hgr - mu3) * r3 * g_hg[c]        + be_hg[c];
    float pz = (x_igz - mu0) * r0 * g_ig[c + 1024] + be_ig[c + 1024]
             + (x_hgz - mu3) * r3 * g_hg[c + 1024] + be_hg[c + 1024];
    float pg = (x_igg - mu0) * r0 * g_ig[c + 2048] + be_ig[c + 2048]
             + (x_hgg - mu3) * r3 * g_hg[c + 2048] + be_hg[c + 2048];

    float rr = 1.f / (1.f + __expf(-pr));
    float zz = 1.f / (1.f + __expf(-pz));
    float gg = 1.f / (1.f + __expf(-pg));

    float Hx = (x_ii - mu1) * r1 * g_ii[c] + be_ii[c];
    float xh = (x_ih - mu2) * r2 * g_ih[c] + be_ih[c];
    float hh = (x_hh - mu4) * r4 * g_hh[c] + be_hh[c];

    float hm = tanhf((1.f - rr) * xh + rr * hh);
    float h  = hrow[c];
    out[row * 1024 + c] = ((1.f - zz) * h + zz * hm) * (1.f - gg) + gg * Hx;
  }
}

extern "C" void kernel_launch(void* const* d_in, const int* in_sizes, int n_in,
                              void* d_out, int out_size, void* d_ws, size_t ws_size,
                              hipStream_t stream) {
  const float* inp      = (const float*)d_in[0];
  const float* hidden   = (const float*)d_in[1];
  const float* W_i2gate = (const float*)d_in[2];
  const float* b_i2gate = (const float*)d_in[3];
  const float* W_h2gate = (const float*)d_in[4];
  const float* b_h2gate = (const float*)d_in[5];
  const float* W_i2i    = (const float*)d_in[6];
  const float* b_i2i    = (const float*)d_in[7];
  const float* W_i2h    = (const float*)d_in[8];
  const float* b_i2h    = (const float*)d_in[9];
  const float* W_h2h    = (const float*)d_in[10];
  const float* b_h2h    = (const float*)d_in[11];
  const float* g_ig  = (const float*)d_in[12];
  const float* be_ig = (const float*)d_in[13];
  const float* g_hg  = (const float*)d_in[14];
  const float* be_hg = (const float*)d_in[15];
  const float* g_ii  = (const float*)d_in[16];
  const float* be_ii = (const float*)d_in[17];
  const float* g_ih  = (const float*)d_in[18];
  const float* be_ih = (const float*)d_in[19];
  const float* g_hh  = (const float*)d_in[20];
  const float* be_hh = (const float*)d_in[21];
  float* out = (float*)d_out;

  const size_t WCAT_B  = (size_t)NCOLS * KDIM * 2;     // 18,874,368
  const size_t BCAT_B  = (size_t)NCOLS * 4;            // 36,864
  const size_t FIXED_B = WCAT_B + BCAT_B;
  const size_t PER_ROW = 2048 + 2048 + 18432;          // 22,528

  if (ws_size < FIXED_B + PER_ROW * 256) return;       // visible fail, no OOB

  char* ws = (char*)d_ws;
  bf16_t* Wcat = (bf16_t*)ws;
  float*  bcat = (float*)(ws + WCAT_B);
  char*   dyn  = ws + FIXED_B;

  size_t max_rows = (ws_size - FIXED_B) / PER_ROW;
  int chunk = (int)((max_rows / 256) * 256);
  if (chunk > BATCH) chunk = BATCH;

  bf16_t* inpb  = (bf16_t*)dyn;
  bf16_t* hidb  = (bf16_t*)(dyn + (size_t)chunk * 2048);
  bf16_t* preLN = (bf16_t*)(dyn + (size_t)chunk * 4096);

  if (chunk == BATCH) {
    const int nact = BATCH * KDIM / 4;
    const int ntot = 2361600 + 2 * nact;
    cast_all<<<(ntot + 255) / 256, 256, 0, stream>>>(
        W_i2gate, W_i2i, W_i2h, W_h2gate, W_h2h,
        b_i2gate, b_i2i, b_i2h, b_h2gate, b_h2h,
        inp, hidden, Wcat, bcat, inpb, hidb, nact, ntot);

    int nbm = BATCH / BMg;   // 64
    gemm_preln<<<nbm * NBN, 512, 0, stream>>>(inpb, hidb, Wcat, bcat, preLN, nbm);

    ln_combine<<<BATCH, 256, 0, stream>>>(preLN, hidden,
                                          g_ig, be_ig, g_hg, be_hg,
                                          g_ii, be_ii, g_ih, be_ih, g_hh, be_hh,
                                          out);
  } else {
    const int ntot_w = 2361600;
    cast_all<<<(ntot_w + 255) / 256, 256, 0, stream>>>(
        W_i2gate, W_i2i, W_i2h, W_h2gate, W_h2h,
        b_i2gate, b_i2i, b_i2h, b_h2gate, b_h2h,
        nullptr, nullptr, Wcat, bcat, nullptr, nullptr, 0, ntot_w);

    for (int r0 = 0; r0 < BATCH; r0 += chunk) {
      int cr = BATCH - r0;
      if (cr > chunk) cr = chunk;
      int n4 = cr * KDIM / 4;
      cast_acts<<<(2 * n4 + 255) / 256, 256, 0, stream>>>(
          inp + (size_t)r0 * KDIM, hidden + (size_t)r0 * KDIM, inpb, hidb, n4);

      int nbm = cr / BMg;
      gemm_preln<<<nbm * NBN, 512, 0, stream>>>(inpb, hidb, Wcat, bcat, preLN, nbm);

      ln_combine<<<cr, 256, 0, stream>>>(preLN, hidden + (size_t)r0 * KDIM,
                                         g_ig, be_ig, g_hg, be_hg,
                                         g_ii, be_ii, g_ih, be_ih, g_hh, be_hh,
                                         out + (size_t)r0 * KDIM);
    }
  }
}

// Round 10
// 499.727 us; speedup vs baseline: 1.3631x; 1.0709x over previous
//
#include <hip/hip_runtime.h>

typedef __bf16 bf16_t;
typedef bf16_t bf16x8 __attribute__((ext_vector_type(8)));
typedef bf16_t bf16x4 __attribute__((ext_vector_type(4)));
typedef float f32x4 __attribute__((ext_vector_type(4)));

#define BATCH 16384
#define KDIM  1024
#define NCOLS 9216   // [0,3072) ig | [3072,4096) ii | [4096,5120) ih | [5120,8192) hg | [8192,9216) hh

#define BMg 256
#define BNg 256
#define BKg 64
#define NTg (KDIM / BKg)   // 16 K-tiles
#define NBN (NCOLS / BNg)  // 36

// ---------------- one-dispatch cast/concat (R6, measured-good) ----------------
__global__ __launch_bounds__(256)
void cast_all(const float* __restrict__ Wig, const float* __restrict__ Wii,
              const float* __restrict__ Wih, const float* __restrict__ Whg,
              const float* __restrict__ Whh,
              const float* __restrict__ big, const float* __restrict__ bii,
              const float* __restrict__ bih, const float* __restrict__ bhg,
              const float* __restrict__ bhh,
              const float* __restrict__ inp, const float* __restrict__ hid,
              bf16_t* __restrict__ Wcat, float* __restrict__ bcat,
              bf16_t* __restrict__ inpb, bf16_t* __restrict__ hidb,
              int nact_units, int ntot)
{
  int u = blockIdx.x * 256 + threadIdx.x;
  if (u >= ntot) return;

  if (u < 2359296) {   // weights
    const float* src; int off;
    if      (u < 786432)  { src = Wig; off = u; }
    else if (u < 1048576) { src = Wii; off = u - 786432; }
    else if (u < 1310720) { src = Wih; off = u - 1048576; }
    else if (u < 2097152) { src = Whg; off = u - 1310720; }
    else                  { src = Whh; off = u - 2097152; }
    float4 v = reinterpret_cast<const float4*>(src)[off];
    bf16x4 o;
    o[0] = (bf16_t)v.x; o[1] = (bf16_t)v.y; o[2] = (bf16_t)v.z; o[3] = (bf16_t)v.w;
    reinterpret_cast<bf16x4*>(Wcat)[u] = o;
  } else if (u < 2361600) {  // biases
    int bu = u - 2359296;
    int i = bu * 4;
    const float* src; int off;
    if      (i < 3072) { src = big; off = i; }
    else if (i < 4096) { src = bii; off = i - 3072; }
    else if (i < 5120) { src = bih; off = i - 4096; }
    else if (i < 8192) { src = bhg; off = i - 5120; }
    else               { src = bhh; off = i - 8192; }
    reinterpret_cast<float4*>(bcat)[bu] = *reinterpret_cast<const float4*>(src + off);
  } else {                    // activations
    int au = u - 2361600;
    const float* src; bf16_t* dst; int off;
    if (au < nact_units) { src = inp; dst = inpb; off = au; }
    else                 { src = hid; dst = hidb; off = au - nact_units; }
    float4 v = reinterpret_cast<const float4*>(src)[off];
    bf16x4 o;
    o[0] = (bf16_t)v.x; o[1] = (bf16_t)v.y; o[2] = (bf16_t)v.z; o[3] = (bf16_t)v.w;
    reinterpret_cast<bf16x4*>(dst)[off] = o;
  }
}

__global__ __launch_bounds__(256)
void cast_acts(const float* __restrict__ inp, const float* __restrict__ hid,
               bf16_t* __restrict__ inpb, bf16_t* __restrict__ hidb, int n4) {
  int i = blockIdx.x * 256 + threadIdx.x;
  if (i >= 2 * n4) return;
  const float* src = (i < n4) ? inp : hid;
  bf16_t* dst = (i < n4) ? inpb : hidb;
  int off = (i < n4) ? i : i - n4;
  float4 v = reinterpret_cast<const float4*>(src)[off];
  bf16x4 o;
  o[0] = (bf16_t)v.x; o[1] = (bf16_t)v.y; o[2] = (bf16_t)v.z; o[3] = (bf16_t)v.w;
  reinterpret_cast<bf16x4*>(dst)[off] = o;
}

// ---------------- GEMM: 256x256, BK=64, 8 waves, Gray-code phases + register carry ----------------
// R9 structure (swizzle, staging, vmcnt schedule identical). Single change: phase order
// (qm,qn) = (0,0)->(0,1)->(1,1)->(1,0) with A held in regs across each qm-pair and both
// B quadrant sets held for the whole K-tile -> 24 unique ds_read_b128 per K-tile (was 48).
// LDS-read deaths only move EARLIER, so R9's verified staging/death schedule is unchanged.
__global__ __launch_bounds__(512, 2)
void gemm_preln(const bf16_t* __restrict__ inpb, const bf16_t* __restrict__ hidb,
                const bf16_t* __restrict__ Wcat, const float* __restrict__ bcat,
                bf16_t* __restrict__ preLN, int nbm)
{
  __shared__ alignas(16) char lds_raw[131072];

  const int tid  = threadIdx.x;
  const int wid  = tid >> 6;         // 0..7
  const int lane = tid & 63;
  const int fr   = lane & 15;
  const int kg   = lane >> 4;        // 0..3
  const int wr   = wid >> 2;         // 0..1
  const int wc   = wid & 3;          // 0..3

  // XCD-aware bijective block swizzle
  const int nwg = nbm * NBN;
  int orig = blockIdx.x;
  int q_ = nwg >> 3, r_ = nwg & 7, xcd = orig & 7, idx = orig >> 3;
  int wg = (xcd < r_ ? xcd * (q_ + 1) : r_ * (q_ + 1) + (xcd - r_) * q_) + idx;
  const int bm = wg / NBN, bn = wg % NBN;
  const int row0 = bm * BMg, col0 = bn * BNg;
  const bf16_t* __restrict__ act = (col0 < 5120) ? inpb : hidb;
  const bf16_t* __restrict__ wgt = Wcat + (size_t)col0 * KDIM;

  // staging source: thread covers (r_st, swizzled k8) of each [128][32] kpanel
  const int r_st  = tid >> 2;                       // 0..127
  const int k8_st = (tid & 3) ^ ((r_st >> 1) & 3);  // inverse swizzle on source
  const bf16_t* pA = act + (size_t)(row0 + r_st) * KDIM + k8_st * 8;
  const bf16_t* pB = wgt + (size_t)r_st * KDIM + k8_st * 8;

  auto stage_half = [&](int mat, int h, int T) {
    const bf16_t* s = (mat ? pB : pA) + ((size_t)h * 128) * KDIM + T * BKg;
    char* d = lds_raw + ((T & 1) << 16) + (mat << 15) + (h << 14) + (wid << 10);
    __builtin_amdgcn_global_load_lds(
        (const __attribute__((address_space(1))) unsigned int*)s,
        (__attribute__((address_space(3))) unsigned int*)d, 16, 0, 0);
    __builtin_amdgcn_global_load_lds(
        (const __attribute__((address_space(1))) unsigned int*)(s + 32),
        (__attribute__((address_space(3))) unsigned int*)(d + 8192), 16, 0, 0);
  };

  // ds-read offsets (within a 16-KiB half region), swizzled slot
  int offA[4][2], offB[2][2];
  #pragma unroll
  for (int m = 0; m < 4; ++m)
    #pragma unroll
    for (int ks = 0; ks < 2; ++ks) {
      const int rowA = wr * 64 + m * 16 + fr;
      offA[m][ks] = ks * 8192 + rowA * 64 + ((kg ^ ((rowA >> 1) & 3)) << 4);
    }
  #pragma unroll
  for (int n = 0; n < 2; ++n)
    #pragma unroll
    for (int ks = 0; ks < 2; ++ks) {
      const int rowB = wc * 32 + n * 16 + fr;
      offB[n][ks] = ks * 8192 + rowB * 64 + ((kg ^ ((rowB >> 1) & 3)) << 4);
    }

  f32x4 acc[2][4][2][2] = {};   // [qm][m][qn][n]

  // prologue: tile0 all 4 halves + tile1 h0 halves (12 loads)
  stage_half(0, 0, 0); stage_half(1, 0, 0);
  stage_half(0, 1, 0); stage_half(1, 1, 0);
  stage_half(0, 0, 1); stage_half(1, 0, 1);
  asm volatile("s_waitcnt vmcnt(4)" ::: "memory");
  __builtin_amdgcn_s_barrier();

  for (int T = 0; T < NTg; ++T) {
    const int bufo = (T & 1) << 16;
    bf16x8 a[4][2], b0[2][2], b1[2][2];

    // ---- ph0 (qm0, qn0): read A0 + B0; stage A-h1(T+1) ----
    #pragma unroll
    for (int m = 0; m < 4; ++m)
      #pragma unroll
      for (int ks = 0; ks < 2; ++ks)
        a[m][ks] = *(const bf16x8*)(lds_raw + bufo + offA[m][ks]);
    #pragma unroll
    for (int n = 0; n < 2; ++n)
      #pragma unroll
      for (int ks = 0; ks < 2; ++ks)
        b0[n][ks] = *(const bf16x8*)(lds_raw + bufo + 32768 + offB[n][ks]);
    if (T + 1 < NTg) stage_half(0, 1, T + 1);
    __builtin_amdgcn_s_barrier();
    asm volatile("s_waitcnt lgkmcnt(0)" ::: "memory");
    __builtin_amdgcn_sched_barrier(0);
    __builtin_amdgcn_s_setprio(1);
    #pragma unroll
    for (int m = 0; m < 4; ++m)
      #pragma unroll
      for (int n = 0; n < 2; ++n)
        #pragma unroll
        for (int ks = 0; ks < 2; ++ks)
          acc[0][m][0][n] = __builtin_amdgcn_mfma_f32_16x16x32_bf16(a[m][ks], b0[n][ks], acc[0][m][0][n], 0, 0, 0);
    __builtin_amdgcn_s_setprio(0);
    __builtin_amdgcn_s_barrier();

    // ---- ph1 (qm0, qn1): read B1; stage B-h1(T+1); A reused ----
    #pragma unroll
    for (int n = 0; n < 2; ++n)
      #pragma unroll
      for (int ks = 0; ks < 2; ++ks)
        b1[n][ks] = *(const bf16x8*)(lds_raw + bufo + 32768 + 16384 + offB[n][ks]);
    if (T + 1 < NTg) stage_half(1, 1, T + 1);
    __builtin_amdgcn_s_barrier();
    asm volatile("s_waitcnt lgkmcnt(0)" ::: "memory");
    __builtin_amdgcn_sched_barrier(0);
    __builtin_amdgcn_s_setprio(1);
    #pragma unroll
    for (int m = 0; m < 4; ++m)
      #pragma unroll
      for (int n = 0; n < 2; ++n)
        #pragma unroll
        for (int ks = 0; ks < 2; ++ks)
          acc[0][m][1][n] = __builtin_amdgcn_mfma_f32_16x16x32_bf16(a[m][ks], b1[n][ks], acc[0][m][1][n], 0, 0, 0);
    __builtin_amdgcn_s_setprio(0);
    __builtin_amdgcn_s_barrier();

    // ---- ph2 (qm1, qn1): read A1; stage A-h0(T+2); B1 reused ----
    #pragma unroll
    for (int m = 0; m < 4; ++m)
      #pragma unroll
      for (int ks = 0; ks < 2; ++ks)
        a[m][ks] = *(const bf16x8*)(lds_raw + bufo + 16384 + offA[m][ks]);
    if (T + 2 < NTg) stage_half(0, 0, T + 2);
    __builtin_amdgcn_s_barrier();
    asm volatile("s_waitcnt lgkmcnt(0)" ::: "memory");
    __builtin_amdgcn_sched_barrier(0);
    __builtin_amdgcn_s_setprio(1);
    #pragma unroll
    for (int m = 0; m < 4; ++m)
      #pragma unroll
      for (int n = 0; n < 2; ++n)
        #pragma unroll
        for (int ks = 0; ks < 2; ++ks)
          acc[1][m][1][n] = __builtin_amdgcn_mfma_f32_16x16x32_bf16(a[m][ks], b1[n][ks], acc[1][m][1][n], 0, 0, 0);
    __builtin_amdgcn_s_setprio(0);
    __builtin_amdgcn_s_barrier();

    // ---- ph3 (qm1, qn0): no reads; stage B-h0(T+2); A1 + held B0 ----
    if (T + 2 < NTg) stage_half(1, 0, T + 2);
    __builtin_amdgcn_s_barrier();
    __builtin_amdgcn_s_setprio(1);
    #pragma unroll
    for (int m = 0; m < 4; ++m)
      #pragma unroll
      for (int n = 0; n < 2; ++n)
        #pragma unroll
        for (int ks = 0; ks < 2; ++ks)
          acc[1][m][0][n] = __builtin_amdgcn_mfma_f32_16x16x32_bf16(a[m][ks], b0[n][ks], acc[1][m][0][n], 0, 0, 0);
    __builtin_amdgcn_s_setprio(0);

    // group end: counted drain + barrier (skip after the last group)
    if (T < NTg - 2) {
      asm volatile("s_waitcnt vmcnt(4)" ::: "memory");
      __builtin_amdgcn_s_barrier();
    } else if (T == NTg - 2) {
      asm volatile("s_waitcnt vmcnt(0)" ::: "memory");
      __builtin_amdgcn_s_barrier();
    }
  }

  // epilogue: bias + bf16 store. C/D 16x16: col=lane&15, row=(lane>>4)*4+j (verified R2)
  #pragma unroll
  for (int qn_ = 0; qn_ < 2; ++qn_)
    #pragma unroll
    for (int n = 0; n < 2; ++n) {
      const int col = col0 + qn_ * 128 + wc * 32 + n * 16 + fr;
      const float bias = bcat[col];
      #pragma unroll
      for (int qm_ = 0; qm_ < 2; ++qm_)
        #pragma unroll
        for (int m = 0; m < 4; ++m) {
          const int rbase = row0 + qm_ * 128 + wr * 64 + m * 16 + kg * 4;
          #pragma unroll
          for (int j = 0; j < 4; ++j)
            preLN[(size_t)(rbase + j) * NCOLS + col] = (bf16_t)(acc[qm_][m][qn_][n][j] + bias);
        }
    }
}

// ---------------- fused LN + gates + combine: vectorized compute phase ----------------
__global__ __launch_bounds__(256)
void ln_combine(const bf16_t* __restrict__ preLN, const float* __restrict__ hidden,
                const float* __restrict__ g_ig, const float* __restrict__ be_ig,
                const float* __restrict__ g_hg, const float* __restrict__ be_hg,
                const float* __restrict__ g_ii, const float* __restrict__ be_ii,
                const float* __restrict__ g_ih, const float* __restrict__ be_ih,
                const float* __restrict__ g_hh, const float* __restrict__ be_hh,
                float* __restrict__ out)
{
  __shared__ alignas(16) bf16_t rowbuf[NCOLS];
  __shared__ float wsum[4][10];
  __shared__ float stats[10];
  const int tid = threadIdx.x;
  const int wv  = tid >> 6;
  const int ln  = tid & 63;
  const size_t row = blockIdx.x;
  const bf16_t* __restrict__ src = preLN + row * NCOLS;

  float s1[5] = {0.f, 0.f, 0.f, 0.f, 0.f};
  float s2[5] = {0.f, 0.f, 0.f, 0.f, 0.f};
  #pragma unroll
  for (int j = 0; j < 9; ++j) {
    const int idx = j * 1024 + tid * 4;
    bf16x4 v = *(const bf16x4*)&src[idx];
    *(bf16x4*)&rowbuf[idx] = v;
    const int sg = (j < 3) ? 0 : (j == 3) ? 1 : (j == 4) ? 2 : (j < 8) ? 3 : 4;
    const float f0 = (float)v[0], f1 = (float)v[1], f2 = (float)v[2], f3 = (float)v[3];
    s1[sg] += f0 + f1 + f2 + f3;
    s2[sg] += f0 * f0 + f1 * f1 + f2 * f2 + f3 * f3;
  }
  #pragma unroll
  for (int s = 0; s < 5; ++s)
    #pragma unroll
    for (int off = 32; off; off >>= 1) {
      s1[s] += __shfl_xor(s1[s], off);
      s2[s] += __shfl_xor(s2[s], off);
    }
  if (ln == 0) {
    #pragma unroll
    for (int s = 0; s < 5; ++s) { wsum[wv][s] = s1[s]; wsum[wv][5 + s] = s2[s]; }
  }
  __syncthreads();
  if (tid < 5) {
    const float n = (tid == 0 || tid == 3) ? 3072.f : 1024.f;
    float t1 = wsum[0][tid] + wsum[1][tid] + wsum[2][tid] + wsum[3][tid];
    float t2 = wsum[0][5 + tid] + wsum[1][5 + tid] + wsum[2][5 + tid] + wsum[3][5 + tid];
    float mu = t1 / n;
    float var = t2 / n - mu * mu;
    stats[tid] = mu;
    stats[5 + tid] = rsqrtf(var + 1e-5f);
  }
  __syncthreads();

  const float mu0 = stats[0], r0 = stats[5];
  const float mu1 = stats[1], r1 = stats[6];
  const float mu2 = stats[2], r2 = stats[7];
  const float mu3 = stats[3], r3 = stats[8];
  const float mu4 = stats[4], r4 = stats[9];
  const float* __restrict__ hrow = hidden + row * 1024;

  // 4 cols/thread, all LDS reads b64 (bf16x4), params f32x4, fully coalesced
  const int c = tid * 4;
  bf16x4 v_igr = *(const bf16x4*)&rowbuf[c];
  bf16x4 v_igz = *(const bf16x4*)&rowbuf[c + 1024];
  bf16x4 v_igg = *(const bf16x4*)&rowbuf[c + 2048];
  bf16x4 v_ii  = *(const bf16x4*)&rowbuf[c + 3072];
  bf16x4 v_ih  = *(const bf16x4*)&rowbuf[c + 4096];
  bf16x4 v_hgr = *(const bf16x4*)&rowbuf[c + 5120];
  bf16x4 v_hgz = *(const bf16x4*)&rowbuf[c + 6144];
  bf16x4 v_hgg = *(const bf16x4*)&rowbuf[c + 7168];
  bf16x4 v_hh  = *(const bf16x4*)&rowbuf[c + 8192];

  f32x4 Gr  = *(const f32x4*)&g_ig[c];        f32x4 Br  = *(const f32x4*)&be_ig[c];
  f32x4 Gz  = *(const f32x4*)&g_ig[c + 1024]; f32x4 Bz  = *(const f32x4*)&be_ig[c + 1024];
  f32x4 Gg  = *(const f32x4*)&g_ig[c + 2048]; f32x4 Bg  = *(const f32x4*)&be_ig[c + 2048];
  f32x4 Hr  = *(const f32x4*)&g_hg[c];        f32x4 Cr  = *(const f32x4*)&be_hg[c];
  f32x4 Hz  = *(const f32x4*)&g_hg[c + 1024]; f32x4 Cz  = *(const f32x4*)&be_hg[c + 1024];
  f32x4 Hg  = *(const f32x4*)&g_hg[c + 2048]; f32x4 Cg  = *(const f32x4*)&be_hg[c + 2048];
  f32x4 Gii = *(const f32x4*)&g_ii[c];        f32x4 Bii = *(const f32x4*)&be_ii[c];
  f32x4 Gih = *(const f32x4*)&g_ih[c];        f32x4 Bih = *(const f32x4*)&be_ih[c];
  f32x4 Ghh = *(const f32x4*)&g_hh[c];        f32x4 Bhh = *(const f32x4*)&be_hh[c];
  f32x4 hv  = *(const f32x4*)&hrow[c];

  f32x4 o;
  #pragma unroll
  for (int i = 0; i < 4; ++i) {
    float pr = ((float)v_igr[i] - mu0) * r0 * Gr[i] + Br[i]
             + ((float)v_hgr[i] - mu3) * r3 * Hr[i] + Cr[i];
    float pz = ((float)v_igz[i] - mu0) * r0 * Gz[i] + Bz[i]
             + ((float)v_hgz[i] - mu3) * r3 * Hz[i] + Cz[i];
    float pg = ((float)v_igg[i] - mu0) * r0 * Gg[i] + Bg[i]
             + ((float)v_hgg[i] - mu3) * r3 * Hg[i] + Cg[i];

    float rr = 1.f / (1.f + __expf(-pr));
    float zz = 1.f / (1.f + __expf(-pz));
    float gg = 1.f / (1.f + __expf(-pg));

    float Hx = ((float)v_ii[i] - mu1) * r1 * Gii[i] + Bii[i];
    float xh = ((float)v_ih[i] - mu2) * r2 * Gih[i] + Bih[i];
    float hh = ((float)v_hh[i] - mu4) * r4 * Ghh[i] + Bhh[i];

    float pre = (1.f - rr) * xh + rr * hh;
    float hm  = 1.f - 2.f / (1.f + __expf(2.f * pre));   // tanh
    o[i] = ((1.f - zz) * hv[i] + zz * hm) * (1.f - gg) + gg * Hx;
  }
  *(f32x4*)&out[row * 1024 + c] = o;
}

extern "C" void kernel_launch(void* const* d_in, const int* in_sizes, int n_in,
                              void* d_out, int out_size, void* d_ws, size_t ws_size,
                              hipStream_t stream) {
  const float* inp      = (const float*)d_in[0];
  const float* hidden   = (const float*)d_in[1];
  const float* W_i2gate = (const float*)d_in[2];
  const float* b_i2gate = (const float*)d_in[3];
  const float* W_h2gate = (const float*)d_in[4];
  const float* b_h2gate = (const float*)d_in[5];
  const float* W_i2i    = (const float*)d_in[6];
  const float* b_i2i    = (const float*)d_in[7];
  const float* W_i2h    = (const float*)d_in[8];
  const float* b_i2h    = (const float*)d_in[9];
  const float* W_h2h    = (const float*)d_in[10];
  const float* b_h2h    = (const float*)d_in[11];
  const float* g_ig  = (const float*)d_in[12];
  const float* be_ig = (const float*)d_in[13];
  const float* g_hg  = (const float*)d_in[14];
  const float* be_hg = (const float*)d_in[15];
  const float* g_ii  = (const float*)d_in[16];
  const float* be_ii = (const float*)d_in[17];
  const float* g_ih  = (const float*)d_in[18];
  const float* be_ih = (const float*)d_in[19];
  const float* g_hh  = (const float*)d_in[20];
  const float* be_hh = (const float*)d_in[21];
  float* out = (float*)d_out;

  const size_t WCAT_B  = (size_t)NCOLS * KDIM * 2;     // 18,874,368
  const size_t BCAT_B  = (size_t)NCOLS * 4;            // 36,864
  const size_t FIXED_B = WCAT_B + BCAT_B;
  const size_t PER_ROW = 2048 + 2048 + 18432;          // 22,528

  if (ws_size < FIXED_B + PER_ROW * 256) return;       // visible fail, no OOB

  char* ws = (char*)d_ws;
  bf16_t* Wcat = (bf16_t*)ws;
  float*  bcat = (float*)(ws + WCAT_B);
  char*   dyn  = ws + FIXED_B;

  size_t max_rows = (ws_size - FIXED_B) / PER_ROW;
  int chunk = (int)((max_rows / 256) * 256);
  if (chunk > BATCH) chunk = BATCH;

  bf16_t* inpb  = (bf16_t*)dyn;
  bf16_t* hidb  = (bf16_t*)(dyn + (size_t)chunk * 2048);
  bf16_t* preLN = (bf16_t*)(dyn + (size_t)chunk * 4096);

  if (chunk == BATCH) {
    const int nact = BATCH * KDIM / 4;
    const int ntot = 2361600 + 2 * nact;
    cast_all<<<(ntot + 255) / 256, 256, 0, stream>>>(
        W_i2gate, W_i2i, W_i2h, W_h2gate, W_h2h,
        b_i2gate, b_i2i, b_i2h, b_h2gate, b_h2h,
        inp, hidden, Wcat, bcat, inpb, hidb, nact, ntot);

    int nbm = BATCH / BMg;   // 64
    gemm_preln<<<nbm * NBN, 512, 0, stream>>>(inpb, hidb, Wcat, bcat, preLN, nbm);

    ln_combine<<<BATCH, 256, 0, stream>>>(preLN, hidden,
                                          g_ig, be_ig, g_hg, be_hg,
                                          g_ii, be_ii, g_ih, be_ih, g_hh, be_hh,
                                          out);
  } else {
    const int ntot_w = 2361600;
    cast_all<<<(ntot_w + 255) / 256, 256, 0, stream>>>(
        W_i2gate, W_i2i, W_i2h, W_h2gate, W_h2h,
        b_i2gate, b_i2i, b_i2h, b_h2gate, b_h2h,
        nullptr, nullptr, Wcat, bcat, nullptr, nullptr, 0, ntot_w);

    for (int r0 = 0; r0 < BATCH; r0 += chunk) {
      int cr = BATCH - r0;
      if (cr > chunk) cr = chunk;
      int n4 = cr * KDIM / 4;
      cast_acts<<<(2 * n4 + 255) / 256, 256, 0, stream>>>(
          inp + (size_t)r0 * KDIM, hidden + (size_t)r0 * KDIM, inpb, hidb, n4);

      int nbm = cr / BMg;
      gemm_preln<<<nbm * NBN, 512, 0, stream>>>(inpb, hidb, Wcat, bcat, preLN, nbm);

      ln_combine<<<cr, 256, 0, stream>>>(preLN, hidden + (size_t)r0 * KDIM,
                                         g_ig, be_ig, g_hg, be_hg,
                                         g_ii, be_ii, g_ih, be_ih, g_hh, be_hh,
                                         out + (size_t)r0 * KDIM);
    }
  }
}